// Round 1
// baseline (9207.927 us; speedup 1.0000x reference)
//
#include <hip/hip_runtime.h>

#define NE 8192
#define NI 2048
#define NN 10240
#define BB 16
#define TT 100
#define STRIDE 704

#define EXP_SYN_C 0.6065306597126334f
#define DT_SYN_C 0.5f
#define EXP_NMDA_C 0.951229424500714f
#define EXP_TAU_C 0.6065306597126334f
#define DT_TAU_C 0.5f
#define USE_C 0.03f
#define SQRTK 22.62741699796952f
#define C_EI (-1.5f / SQRTK)
#define C_IE (1.0f / SQRTK)
#define C_II (-1.0f / SQRTK)
#define C_STP (1.0f / 512.0f)

// ---------------- build per-post index lists ----------------
// Wab_T is (NN, NN) row-major: element (m=pre, n=post). EE block is zero.
// nonzero m<NE  -> listA[n] (only happens for n>=NE)
// nonzero m>=NE -> listB[n]
__global__ void build_wab(const float* __restrict__ W,
                          unsigned short* __restrict__ idxA,
                          unsigned short* __restrict__ idxB,
                          unsigned* __restrict__ cntA,
                          unsigned* __restrict__ cntB) {
    const int n = blockIdx.x * blockDim.x + threadIdx.x;  // column (post)
    const int m0 = blockIdx.y * (NN / 16);
    const int m1 = m0 + (NN / 16);
    for (int m = m0; m < m1; ++m) {
        float v = W[(size_t)m * NN + n];
        if (v != 0.0f) {
            if (m < NE) {
                unsigned p = atomicAdd(&cntA[n], 1u);
                if (p < STRIDE) idxA[(size_t)n * STRIDE + p] = (unsigned short)m;
            } else {
                unsigned p = atomicAdd(&cntB[n], 1u);
                if (p < STRIDE) idxB[(size_t)n * STRIDE + p] = (unsigned short)m;
            }
        }
    }
}

// W_stp_T is (NE, NE): nonzero (m, n) -> listA[n]  (n < NE; disjoint from above)
__global__ void build_stp(const float* __restrict__ W,
                          unsigned short* __restrict__ idxA,
                          unsigned* __restrict__ cntA) {
    const int n = blockIdx.x * blockDim.x + threadIdx.x;  // 0..NE-1
    const int m0 = blockIdx.y * (NE / 16);
    const int m1 = m0 + (NE / 16);
    for (int m = m0; m < m1; ++m) {
        float v = W[(size_t)m * NE + n];
        if (v != 0.0f) {
            unsigned p = atomicAdd(&cntA[n], 1u);
            if (p < STRIDE) idxA[(size_t)n * STRIDE + p] = (unsigned short)m;
        }
    }
}

// ---------------- init: transpose state to [n][b], compute r_init, u/x/aux for t=0 --
__global__ void init_state(const float* __restrict__ ff, const float* __restrict__ rec_in,
                           float* __restrict__ rates0, float* __restrict__ rec0,
                           float* __restrict__ rec1, float* __restrict__ u,
                           float* __restrict__ x, float* __restrict__ aux0) {
    int t = blockIdx.x * blockDim.x + threadIdx.x;  // over B*NN, n fastest
    if (t >= BB * NN) return;
    int b = t / NN, n = t - b * NN;
    float r0c = rec_in[(size_t)b * NN + n];
    float r1c = rec_in[(size_t)(BB + b) * NN + n];
    float f = ff[(size_t)b * TT * NN + n];  // ff_input[b, 0, n]
    float r = (f + r0c) - 1.0f;
    r = r > 0.0f ? r : 0.0f;
    size_t o = (size_t)n * BB + b;
    rates0[o] = r;
    rec0[o] = r0c;
    rec1[o] = r1c;
    if (n < NE) {
        float uu = USE_C;
        uu = uu + 0.01f * (USE_C - uu) + USE_C * (1.0f - uu) * r * 0.01f;
        float xx = 1.0f;
        xx = xx + 0.01f * (1.0f - xx) * 4.0f - uu * xx * r * 0.01f;
        u[o] = uu;
        x[o] = xx;
        aux0[o] = uu * xx * r;
    }
}

// ---------------- gather: sum src[m*16+b] over list; 4 pre-slots per wave ----------
__device__ __forceinline__ float gather_sum(const unsigned short* __restrict__ lst,
                                            int cnt, const float* __restrict__ src,
                                            int b, int g) {
    int q = (((cnt + 3) >> 2) + 3) & ~3;  // per-group quota, multiple of 4
    int s = g * q;
    int e = s + q;
    if (e > cnt) e = cnt;
    float a0 = 0.f, a1 = 0.f, a2 = 0.f, a3 = 0.f;
    int nfull = (e > s) ? ((e - s) >> 2) : 0;
    const uint2* lp = (const uint2*)(lst + s);  // s multiple of 4 -> 8B aligned
    for (int i = 0; i < nfull; ++i) {
        uint2 w = lp[i];
        int m0 = (int)(w.x & 0xffffu);
        int m1 = (int)(w.x >> 16);
        int m2 = (int)(w.y & 0xffffu);
        int m3 = (int)(w.y >> 16);
        a0 += src[m0 * BB + b];
        a1 += src[m1 * BB + b];
        a2 += src[m2 * BB + b];
        a3 += src[m3 * BB + b];
    }
    float a = (a0 + a1) + (a2 + a3);
    for (int k = s + (nfull << 2); k < e; ++k) a += src[(int)lst[k] * BB + b];
    return a;
}

// ---------------- one time step: one wave per post-neuron ----------------
__global__ __launch_bounds__(256) void step_kernel(
    const float* __restrict__ ff, int t,
    const unsigned short* __restrict__ idxA, const unsigned short* __restrict__ idxB,
    const unsigned* __restrict__ cntA, const unsigned* __restrict__ cntB,
    const float* __restrict__ rates_cur, float* __restrict__ rates_nxt,
    const float* __restrict__ aux_cur, float* __restrict__ aux_nxt,
    float* __restrict__ u, float* __restrict__ x,
    float* __restrict__ rec0, float* __restrict__ rec1, float* __restrict__ out) {
    const int wave = threadIdx.x >> 6;
    const int lane = threadIdx.x & 63;
    const int n = blockIdx.x * 4 + wave;
    const int b = lane & 15;
    const int g = lane >> 4;

    const float* srcA = (n < NE) ? aux_cur : rates_cur;
    float sA = gather_sum(idxA + (size_t)n * STRIDE, (int)cntA[n], srcA, b, g);
    float sB = gather_sum(idxB + (size_t)n * STRIDE, (int)cntB[n], rates_cur, b, g);
    sA += __shfl_xor(sA, 16);
    sA += __shfl_xor(sA, 32);
    sB += __shfl_xor(sB, 16);
    sB += __shfl_xor(sB, 32);

    const size_t o = (size_t)n * BB + b;
    float hidden, hidden2;
    if (n < NE) {
        float h_stp = C_STP * sA;
        hidden = C_EI * sB + h_stp;
        hidden2 = h_stp;
    } else {
        hidden = C_IE * sA + C_II * sB;
        hidden2 = C_IE * sA;
    }
    float r0v = rec0[o] * EXP_SYN_C + hidden * DT_SYN_C;
    float r1v = rec1[o] * EXP_NMDA_C + 0.4f * hidden2 * 0.05f;
    float ffv = ff[(size_t)b * (TT * NN) + (size_t)t * NN + n];
    float net = (ffv + r0v) + r1v;
    float nl = net - 1.0f;
    nl = nl > 0.0f ? nl : 0.0f;
    float rnew = rates_cur[o] * EXP_TAU_C + nl * DT_TAU_C;

    if (g == 0) {
        rec0[o] = r0v;
        rec1[o] = r1v;
        rates_nxt[o] = rnew;
        out[(size_t)b * (TT * NN) + (size_t)t * NN + n] = rnew;
        if (n < NE) {
            float uu = u[o];
            uu = uu + 0.01f * (USE_C - uu) + USE_C * (1.0f - uu) * rnew * 0.01f;
            float xx = x[o];
            xx = xx + 0.01f * (1.0f - xx) * 4.0f - uu * xx * rnew * 0.01f;
            u[o] = uu;
            x[o] = xx;
            aux_nxt[o] = uu * xx * rnew;
        }
    }
}

extern "C" void kernel_launch(void* const* d_in, const int* in_sizes, int n_in,
                              void* d_out, int out_size, void* d_ws, size_t ws_size,
                              hipStream_t stream) {
    const float* ff = (const float*)d_in[0];      // (B, T, N)
    const float* rec = (const float*)d_in[1];     // (2, B, N)
    const float* Wab_T = (const float*)d_in[2];   // (N, N)
    const float* Wstp_T = (const float*)d_in[3];  // (NE, NE)
    float* out = (float*)d_out;

    char* p = (char*)d_ws;
    auto alloc = [&](size_t bytes) {
        char* r = p;
        p += (bytes + 255) & ~(size_t)255;
        return r;
    };
    unsigned short* idxA = (unsigned short*)alloc((size_t)NN * STRIDE * 2);
    unsigned short* idxB = (unsigned short*)alloc((size_t)NN * STRIDE * 2);
    unsigned* cntA = (unsigned*)alloc((size_t)NN * 4);
    unsigned* cntB = (unsigned*)alloc((size_t)NN * 4);
    float* rates0 = (float*)alloc((size_t)NN * BB * 4);
    float* rates1 = (float*)alloc((size_t)NN * BB * 4);
    float* aux0 = (float*)alloc((size_t)NE * BB * 4);
    float* aux1 = (float*)alloc((size_t)NE * BB * 4);
    float* u = (float*)alloc((size_t)NE * BB * 4);
    float* x = (float*)alloc((size_t)NE * BB * 4);
    float* rec0 = (float*)alloc((size_t)NN * BB * 4);
    float* rec1 = (float*)alloc((size_t)NN * BB * 4);

    hipMemsetAsync(cntA, 0, (size_t)NN * 4, stream);
    hipMemsetAsync(cntB, 0, (size_t)NN * 4, stream);
    build_wab<<<dim3(NN / 256, 16), 256, 0, stream>>>(Wab_T, idxA, idxB, cntA, cntB);
    build_stp<<<dim3(NE / 256, 16), 256, 0, stream>>>(Wstp_T, idxA, cntA);
    init_state<<<(BB * NN + 255) / 256, 256, 0, stream>>>(ff, rec, rates0, rec0, rec1, u,
                                                          x, aux0);
    float* rbuf[2] = {rates0, rates1};
    float* abuf[2] = {aux0, aux1};
    for (int t = 0; t < TT; ++t) {
        step_kernel<<<NN / 4, 256, 0, stream>>>(
            ff, t, idxA, idxB, cntA, cntB, rbuf[t & 1], rbuf[(t + 1) & 1], abuf[t & 1],
            abuf[(t + 1) & 1], u, x, rec0, rec1, out);
    }
}

// Round 2
// 6520.353 us; speedup vs baseline: 1.4122x; 1.4122x over previous
//
#include <hip/hip_runtime.h>

#define NE 8192
#define NI 2048
#define NN 10240
#define BB 16
#define TT 100
#define STRIDE 704

#define EXP_SYN_C 0.6065306597126334f
#define DT_SYN_C 0.5f
#define EXP_NMDA_C 0.951229424500714f
#define EXP_TAU_C 0.6065306597126334f
#define DT_TAU_C 0.5f
#define USE_C 0.03f
#define SQRTK 22.62741699796952f
#define C_EI (-1.5f / SQRTK)
#define C_IE (1.0f / SQRTK)
#define C_II (-1.0f / SQRTK)
#define C_STP (1.0f / 512.0f)

// ---------------- build per-post index lists ----------------
// Wab_T is (NN, NN) row-major: element (m=pre, n=post). EE block is zero.
// nonzero m<NE  -> listA[n] (only happens for n>=NE)
// nonzero m>=NE -> listB[n]
__device__ __forceinline__ void push_idx(unsigned short* __restrict__ idx,
                                         unsigned* __restrict__ cnt, int n, int m) {
    unsigned p = atomicAdd(&cnt[n], 1u);
    if (p < STRIDE) idx[(size_t)n * STRIDE + p] = (unsigned short)m;
}

__global__ __launch_bounds__(256) void build_wab(const float* __restrict__ W,
                                                 unsigned short* __restrict__ idxA,
                                                 unsigned short* __restrict__ idxB,
                                                 unsigned* __restrict__ cntA,
                                                 unsigned* __restrict__ cntB) {
    const int n4 = blockIdx.x * blockDim.x + threadIdx.x;  // 0..NN/4-1
    const int n = n4 << 2;
    const int m0 = blockIdx.y * (NN / 256);
    const int m1 = m0 + (NN / 256);
    for (int m = m0; m < m1; ++m) {
        float4 v = *(const float4*)&W[(size_t)m * NN + n];
        if (m < NE) {
            if (v.x != 0.0f) push_idx(idxA, cntA, n + 0, m);
            if (v.y != 0.0f) push_idx(idxA, cntA, n + 1, m);
            if (v.z != 0.0f) push_idx(idxA, cntA, n + 2, m);
            if (v.w != 0.0f) push_idx(idxA, cntA, n + 3, m);
        } else {
            if (v.x != 0.0f) push_idx(idxB, cntB, n + 0, m);
            if (v.y != 0.0f) push_idx(idxB, cntB, n + 1, m);
            if (v.z != 0.0f) push_idx(idxB, cntB, n + 2, m);
            if (v.w != 0.0f) push_idx(idxB, cntB, n + 3, m);
        }
    }
}

// W_stp_T is (NE, NE): nonzero (m, n) -> listA[n]  (n < NE; disjoint from above)
__global__ __launch_bounds__(256) void build_stp(const float* __restrict__ W,
                                                 unsigned short* __restrict__ idxA,
                                                 unsigned* __restrict__ cntA) {
    const int n4 = blockIdx.x * blockDim.x + threadIdx.x;  // 0..NE/4-1
    const int n = n4 << 2;
    const int m0 = blockIdx.y * (NE / 256);
    const int m1 = m0 + (NE / 256);
    for (int m = m0; m < m1; ++m) {
        float4 v = *(const float4*)&W[(size_t)m * NE + n];
        if (v.x != 0.0f) push_idx(idxA, cntA, n + 0, m);
        if (v.y != 0.0f) push_idx(idxA, cntA, n + 1, m);
        if (v.z != 0.0f) push_idx(idxA, cntA, n + 2, m);
        if (v.w != 0.0f) push_idx(idxA, cntA, n + 3, m);
    }
}

// ---------------- init: transpose state to [n][b], compute r_init, u/x/aux for t=0 --
__global__ void init_state(const float* __restrict__ ff, const float* __restrict__ rec_in,
                           float* __restrict__ rates0, float* __restrict__ rec0,
                           float* __restrict__ rec1, float* __restrict__ u,
                           float* __restrict__ x, float* __restrict__ aux0) {
    int t = blockIdx.x * blockDim.x + threadIdx.x;  // over B*NN, n fastest
    if (t >= BB * NN) return;
    int b = t / NN, n = t - b * NN;
    float r0c = rec_in[(size_t)b * NN + n];
    float r1c = rec_in[(size_t)(BB + b) * NN + n];
    float f = ff[(size_t)b * TT * NN + n];  // ff_input[b, 0, n]
    float r = (f + r0c) - 1.0f;
    r = r > 0.0f ? r : 0.0f;
    size_t o = (size_t)n * BB + b;
    rates0[o] = r;
    rec0[o] = r0c;
    rec1[o] = r1c;
    if (n < NE) {
        float uu = USE_C;
        uu = uu + 0.01f * (USE_C - uu) + USE_C * (1.0f - uu) * r * 0.01f;
        float xx = 1.0f;
        xx = xx + 0.01f * (1.0f - xx) * 4.0f - uu * xx * r * 0.01f;
        u[o] = uu;
        x[o] = xx;
        aux0[o] = uu * xx * r;
    }
}

// ---------------- gather: wave = 16 edge-slots (e) x 4 batch-quads (q) ----------
// Each lane: ushort index load (broadcast across the 4 q-lanes sharing e) +
// float4 src load covering batches q*4..q*4+3. 2 VMEM instrs per 16 edges.
__device__ __forceinline__ float4 gather16(const unsigned short* __restrict__ lst,
                                           int cnt, const float* __restrict__ src,
                                           int e, int q) {
    float4 acc = {0.f, 0.f, 0.f, 0.f};
    const int qo = q << 2;
    const int rounds = cnt >> 4;
    int r = 0;
    for (; r + 2 <= rounds; r += 2) {
        int p0 = (r << 4) + e;
        int m0 = (int)lst[p0];
        int m1 = (int)lst[p0 + 16];
        float4 v0 = *(const float4*)&src[m0 * BB + qo];
        float4 v1 = *(const float4*)&src[m1 * BB + qo];
        acc.x += v0.x; acc.y += v0.y; acc.z += v0.z; acc.w += v0.w;
        acc.x += v1.x; acc.y += v1.y; acc.z += v1.z; acc.w += v1.w;
    }
    if (r < rounds) {
        int p0 = (r << 4) + e;
        int m0 = (int)lst[p0];
        float4 v0 = *(const float4*)&src[m0 * BB + qo];
        acc.x += v0.x; acc.y += v0.y; acc.z += v0.z; acc.w += v0.w;
    }
    int pos = (rounds << 4) + e;
    if (pos < cnt) {
        int m = (int)lst[pos];
        float4 v = *(const float4*)&src[m * BB + qo];
        acc.x += v.x; acc.y += v.y; acc.z += v.z; acc.w += v.w;
    }
    return acc;
}

__device__ __forceinline__ void reduce_e(float4& a) {
    #pragma unroll
    for (int off = 4; off < 64; off <<= 1) {
        a.x += __shfl_xor(a.x, off);
        a.y += __shfl_xor(a.y, off);
        a.z += __shfl_xor(a.z, off);
        a.w += __shfl_xor(a.w, off);
    }
}

// ---------------- one time step: one wave per post-neuron ----------------
__global__ __launch_bounds__(256) void step_kernel(
    const float* __restrict__ ff, int t,
    const unsigned short* __restrict__ idxA, const unsigned short* __restrict__ idxB,
    const unsigned* __restrict__ cntA, const unsigned* __restrict__ cntB,
    const float* __restrict__ rates_cur, float* __restrict__ rates_nxt,
    const float* __restrict__ aux_cur, float* __restrict__ aux_nxt,
    float* __restrict__ u, float* __restrict__ x,
    float* __restrict__ rec0, float* __restrict__ rec1, float* __restrict__ out) {
    const int wave = threadIdx.x >> 6;
    const int lane = threadIdx.x & 63;
    const int n = blockIdx.x * 4 + wave;
    const int e = lane >> 2;
    const int q = lane & 3;

    const float* srcA = (n < NE) ? aux_cur : rates_cur;
    float4 sA = gather16(idxA + (size_t)n * STRIDE, (int)cntA[n], srcA, e, q);
    float4 sB = gather16(idxB + (size_t)n * STRIDE, (int)cntB[n], rates_cur, e, q);
    reduce_e(sA);
    reduce_e(sB);

    if (lane < 4) {  // e == 0; this lane handles batches q*4 .. q*4+3
        float hA[4] = {sA.x, sA.y, sA.z, sA.w};
        float hB[4] = {sB.x, sB.y, sB.z, sB.w};
        const int b0 = q << 2;
        const size_t o = (size_t)n * BB + b0;
        float4 r0v4 = *(const float4*)&rec0[o];
        float4 r1v4 = *(const float4*)&rec1[o];
        float4 rc4 = *(const float4*)&rates_cur[o];
        float r0a[4] = {r0v4.x, r0v4.y, r0v4.z, r0v4.w};
        float r1a[4] = {r1v4.x, r1v4.y, r1v4.z, r1v4.w};
        float rca[4] = {rc4.x, rc4.y, rc4.z, rc4.w};
        float rna[4];
        #pragma unroll
        for (int c = 0; c < 4; ++c) {
            float hidden, hidden2;
            if (n < NE) {
                float h_stp = C_STP * hA[c];
                hidden = C_EI * hB[c] + h_stp;
                hidden2 = h_stp;
            } else {
                hidden = C_IE * hA[c] + C_II * hB[c];
                hidden2 = C_IE * hA[c];
            }
            float r0n = r0a[c] * EXP_SYN_C + hidden * DT_SYN_C;
            float r1n = r1a[c] * EXP_NMDA_C + 0.4f * hidden2 * 0.05f;
            float ffv = ff[(size_t)(b0 + c) * (TT * NN) + (size_t)t * NN + n];
            float net = (ffv + r0n) + r1n;
            float nl = net - 1.0f;
            nl = nl > 0.0f ? nl : 0.0f;
            float rnew = rca[c] * EXP_TAU_C + nl * DT_TAU_C;
            r0a[c] = r0n;
            r1a[c] = r1n;
            rna[c] = rnew;
            out[(size_t)(b0 + c) * (TT * NN) + (size_t)t * NN + n] = rnew;
        }
        *(float4*)&rec0[o] = make_float4(r0a[0], r0a[1], r0a[2], r0a[3]);
        *(float4*)&rec1[o] = make_float4(r1a[0], r1a[1], r1a[2], r1a[3]);
        *(float4*)&rates_nxt[o] = make_float4(rna[0], rna[1], rna[2], rna[3]);
        if (n < NE) {
            float4 u4 = *(const float4*)&u[o];
            float4 x4 = *(const float4*)&x[o];
            float ua[4] = {u4.x, u4.y, u4.z, u4.w};
            float xa[4] = {x4.x, x4.y, x4.z, x4.w};
            float aa[4];
            #pragma unroll
            for (int c = 0; c < 4; ++c) {
                float uu = ua[c];
                uu = uu + 0.01f * (USE_C - uu) + USE_C * (1.0f - uu) * rna[c] * 0.01f;
                float xx = xa[c];
                xx = xx + 0.01f * (1.0f - xx) * 4.0f - uu * xx * rna[c] * 0.01f;
                ua[c] = uu;
                xa[c] = xx;
                aa[c] = uu * xx * rna[c];
            }
            *(float4*)&u[o] = make_float4(ua[0], ua[1], ua[2], ua[3]);
            *(float4*)&x[o] = make_float4(xa[0], xa[1], xa[2], xa[3]);
            *(float4*)&aux_nxt[o] = make_float4(aa[0], aa[1], aa[2], aa[3]);
        }
    }
}

extern "C" void kernel_launch(void* const* d_in, const int* in_sizes, int n_in,
                              void* d_out, int out_size, void* d_ws, size_t ws_size,
                              hipStream_t stream) {
    const float* ff = (const float*)d_in[0];      // (B, T, N)
    const float* rec = (const float*)d_in[1];     // (2, B, N)
    const float* Wab_T = (const float*)d_in[2];   // (N, N)
    const float* Wstp_T = (const float*)d_in[3];  // (NE, NE)
    float* out = (float*)d_out;

    char* p = (char*)d_ws;
    auto alloc = [&](size_t bytes) {
        char* r = p;
        p += (bytes + 255) & ~(size_t)255;
        return r;
    };
    unsigned short* idxA = (unsigned short*)alloc((size_t)NN * STRIDE * 2);
    unsigned short* idxB = (unsigned short*)alloc((size_t)NN * STRIDE * 2);
    unsigned* cntA = (unsigned*)alloc((size_t)NN * 4);
    unsigned* cntB = (unsigned*)alloc((size_t)NN * 4);
    float* rates0 = (float*)alloc((size_t)NN * BB * 4);
    float* rates1 = (float*)alloc((size_t)NN * BB * 4);
    float* aux0 = (float*)alloc((size_t)NE * BB * 4);
    float* aux1 = (float*)alloc((size_t)NE * BB * 4);
    float* u = (float*)alloc((size_t)NE * BB * 4);
    float* x = (float*)alloc((size_t)NE * BB * 4);
    float* rec0 = (float*)alloc((size_t)NN * BB * 4);
    float* rec1 = (float*)alloc((size_t)NN * BB * 4);

    hipMemsetAsync(cntA, 0, (size_t)NN * 4, stream);
    hipMemsetAsync(cntB, 0, (size_t)NN * 4, stream);
    build_wab<<<dim3(NN / 4 / 256, 256), 256, 0, stream>>>(Wab_T, idxA, idxB, cntA, cntB);
    build_stp<<<dim3(NE / 4 / 256, 256), 256, 0, stream>>>(Wstp_T, idxA, cntA);
    init_state<<<(BB * NN + 255) / 256, 256, 0, stream>>>(ff, rec, rates0, rec0, rec1, u,
                                                          x, aux0);
    float* rbuf[2] = {rates0, rates1};
    float* abuf[2] = {aux0, aux1};
    for (int t = 0; t < TT; ++t) {
        step_kernel<<<NN / 4, 256, 0, stream>>>(
            ff, t, idxA, idxB, cntA, cntB, rbuf[t & 1], rbuf[(t + 1) & 1], abuf[t & 1],
            abuf[(t + 1) & 1], u, x, rec0, rec1, out);
    }
}